// Round 1
// baseline (682.515 us; speedup 1.0000x reference)
//
#include <hip/hip_runtime.h>

#define NB 128   // batch
#define NT 512   // time steps
#define NL 256   // labels

// One workgroup per batch element. 512 threads:
//   thread -> i = tid>>1 (output row), half = tid&1 (j-range [half*128, half*128+128))
// exp(trans[i][j]) held in 128 VGPRs per thread. alpha carried in exp-space in LDS
// (double-buffered), base m is the exact max of alpha, one step stale (safe: growth
// per step <= ~15 in log space, so s <= ~1e11 << f32 max).
__global__ __launch_bounds__(512) void crf_forward(
    const float* __restrict__ emis,
    const float* __restrict__ trans,
    const int*   __restrict__ words,
    float*       __restrict__ bout)
{
    const int b    = blockIdx.x;
    const int tid  = threadIdx.x;
    const int i    = tid >> 1;
    const int half = tid & 1;
    const int lane = tid & 63;
    const int wv   = tid >> 6;   // wave id 0..7

    __shared__ __align__(16) float ea[2][NL];   // exp(alpha - m), double buffered
    __shared__ float wmaxbuf[2][8];             // per-wave maxes, double buffered
    __shared__ float wsum[8];
    __shared__ int   wlds[NT];

    // stage this batch's word indices
    wlds[tid] = words[b * NT + tid];

    // load exp(trans) into registers: mreg[k] = exp(trans[i][half*128 + k])
    float mreg[128];
    {
        const float* tr = trans + i * NL + half * 128;
        #pragma unroll
        for (int k = 0; k < 32; ++k) {
            float4 v = *reinterpret_cast<const float4*>(tr + 4 * k);
            mreg[4*k+0] = __expf(v.x);
            mreg[4*k+1] = __expf(v.y);
            mreg[4*k+2] = __expf(v.z);
            mreg[4*k+3] = __expf(v.w);
        }
    }
    __syncthreads();  // wlds ready

    // prologue: alpha0 = e[:,0]
    float anew = emis[wlds[0] * NL + i];
    float wm = anew;
    #pragma unroll
    for (int off = 32; off; off >>= 1) wm = fmaxf(wm, __shfl_xor(wm, off));
    if (lane == 0) wmaxbuf[0][wv] = wm;
    __syncthreads();
    float m_reg = wmaxbuf[0][0];
    #pragma unroll
    for (int w = 1; w < 8; ++w) m_reg = fmaxf(m_reg, wmaxbuf[0][w]);
    if (half == 0) ea[0][i] = __expf(anew - m_reg);
    __syncthreads();

    int cur = 0;
    for (int t = 1; t < NT; ++t) {
        // issue emission gather early; consumed after the matvec
        float et = emis[wlds[t] * NL + i];

        // exp-space matvec: s_half = sum_j exp(trans[i][j]) * ea[j]
        float acc0 = 0.f, acc1 = 0.f, acc2 = 0.f, acc3 = 0.f;
        const float* eab = &ea[cur][half * 128];
        #pragma unroll
        for (int k = 0; k < 32; ++k) {
            float4 a4 = *reinterpret_cast<const float4*>(eab + 4 * k);  // broadcast
            acc0 = fmaf(mreg[4*k+0], a4.x, acc0);
            acc1 = fmaf(mreg[4*k+1], a4.y, acc1);
            acc2 = fmaf(mreg[4*k+2], a4.z, acc2);
            acc3 = fmaf(mreg[4*k+3], a4.w, acc3);
        }
        float s = (acc0 + acc1) + (acc2 + acc3);
        s += __shfl_xor(s, 1);              // combine the two j-halves

        anew = et + m_reg + __logf(s);

        // wave max of new alpha (values duplicated per i-pair; max unaffected)
        wm = anew;
        #pragma unroll
        for (int off = 32; off; off >>= 1) wm = fmaxf(wm, __shfl_xor(wm, off));
        if (lane == 0) wmaxbuf[t & 1][wv] = wm;

        // stale max from previous step's buffer (visible via last barrier)
        const float* pb = wmaxbuf[(t - 1) & 1];
        float mnew = pb[0];
        #pragma unroll
        for (int w = 1; w < 8; ++w) mnew = fmaxf(mnew, pb[w]);
        m_reg = mnew;

        if (half == 0) ea[cur ^ 1][i] = __expf(anew - m_reg);
        cur ^= 1;
        __syncthreads();   // single barrier per step
    }

    // epilogue: logZ_b = LSE_i(alpha_last)
    wm = anew;
    #pragma unroll
    for (int off = 32; off; off >>= 1) wm = fmaxf(wm, __shfl_xor(wm, off));
    if (lane == 0) wmaxbuf[0][wv] = wm;
    __syncthreads();
    float m = wmaxbuf[0][0];
    #pragma unroll
    for (int w = 1; w < 8; ++w) m = fmaxf(m, wmaxbuf[0][w]);
    float e = (half == 0) ? __expf(anew - m) : 0.f;  // count each i once
    #pragma unroll
    for (int off = 32; off; off >>= 1) e += __shfl_xor(e, off);
    if (lane == 0) wsum[wv] = e;
    __syncthreads();
    if (tid == 0) {
        float ssum = 0.f;
        #pragma unroll
        for (int w = 0; w < 8; ++w) ssum += wsum[w];
        bout[b] = m + __logf(ssum);
    }
}

__global__ void crf_reduce(const float* __restrict__ bout, float* __restrict__ out)
{
    const int tid = threadIdx.x;  // 128 threads
    float v = bout[tid];
    #pragma unroll
    for (int off = 32; off; off >>= 1) v += __shfl_xor(v, off);
    __shared__ float sred[2];
    if ((tid & 63) == 0) sred[tid >> 6] = v;
    __syncthreads();
    if (tid == 0) out[0] = sred[0] + sred[1];
}

extern "C" void kernel_launch(void* const* d_in, const int* in_sizes, int n_in,
                              void* d_out, int out_size, void* d_ws, size_t ws_size,
                              hipStream_t stream)
{
    const float* emis  = (const float*)d_in[0];
    const float* trans = (const float*)d_in[1];
    const int*   words = (const int*)d_in[2];
    float* out  = (float*)d_out;
    float* bout = (float*)d_ws;   // 128 floats of scratch

    crf_forward<<<NB, 512, 0, stream>>>(emis, trans, words, bout);
    crf_reduce<<<1, 128, 0, stream>>>(bout, out);
}

// Round 2
// 530.065 us; speedup vs baseline: 1.2876x; 1.2876x over previous
//
#include <hip/hip_runtime.h>

#define NB 128   // batch
#define NT 512   // time steps
#define NL 256   // labels

typedef _Float16 h2 __attribute__((ext_vector_type(2)));

__device__ inline float dot2(h2 a, h2 b, float c) {
#if __has_builtin(__builtin_amdgcn_fdot2)
    return __builtin_amdgcn_fdot2(a, b, c, false);
#else
    return c + (float)a[0] * (float)b[0] + (float)a[1] * (float)b[1];
#endif
}

// One workgroup (256 threads = 4 waves) per batch element.
// Thread tid owns output row i = tid: holds exp(trans[i][0..255]) as 128 packed
// f16 pairs in VGPRs. exp-space alpha (ea, f16) lives in LDS, double-buffered.
// All 64 lanes of a wave read the SAME ea chunk address -> pure LDS broadcast,
// no bank conflicts. Base m is the exact max of alpha one step stale, plus a
// +4 shift so ea stays ~e^2.5 << f16 max (clamped at 60000 as backstop).
__global__ __launch_bounds__(256, 1) void crf_forward(
    const float* __restrict__ emis,
    const float* __restrict__ trans,
    const int*   __restrict__ words,
    float*       __restrict__ bout)
{
    const int b    = blockIdx.x;
    const int tid  = threadIdx.x;
    const int lane = tid & 63;
    const int wv   = tid >> 6;   // wave id 0..3

    __shared__ __align__(16) h2 ea[2][NL / 2];  // exp(alpha - m_base), f16, dbuf
    __shared__ float wmaxbuf[2][4];
    __shared__ float wsum[4];
    __shared__ int   wlds[NT];

    // stage word indices
    wlds[tid]       = words[b * NT + tid];
    wlds[tid + 256] = words[b * NT + tid + 256];

    // M row: mreg[k] = (f16) { exp(trans[tid][2k]), exp(trans[tid][2k+1]) }
    h2 mreg[128];
    {
        const float* tr = trans + tid * NL;
        #pragma unroll
        for (int k = 0; k < 64; ++k) {
            float4 v = *reinterpret_cast<const float4*>(tr + 4 * k);
            h2 p0, p1;
            p0[0] = (_Float16)__expf(v.x);  p0[1] = (_Float16)__expf(v.y);
            p1[0] = (_Float16)__expf(v.z);  p1[1] = (_Float16)__expf(v.w);
            mreg[2 * k]     = p0;
            mreg[2 * k + 1] = p1;
        }
    }
    __syncthreads();  // wlds ready

    // prologue: alpha0 = e[:,0]; exact max
    float anew = emis[(long)wlds[0] * NL + tid];
    float wm = anew;
    #pragma unroll
    for (int off = 32; off; off >>= 1) wm = fmaxf(wm, __shfl_xor(wm, off));
    if (lane == 0) wmaxbuf[0][wv] = wm;
    __syncthreads();
    float m_base = fmaxf(fmaxf(wmaxbuf[0][0], wmaxbuf[0][1]),
                         fmaxf(wmaxbuf[0][2], wmaxbuf[0][3])) + 4.f;
    {
        float eav = fminf(__expf(anew - m_base), 60000.f);
        reinterpret_cast<_Float16*>(ea[0])[tid] = (_Float16)eav;
    }
    __syncthreads();

    int cur = 0;
    for (int t = 1; t < NT; ++t) {
        // emission gather issued early, consumed after the dot
        float et = emis[(long)wlds[t] * NL + tid];

        // s = sum_j exp(trans[i][j]) * ea[j]   (f16 dot2, f32 accum)
        float acc0 = 0.f, acc1 = 0.f, acc2 = 0.f, acc3 = 0.f;
        const float4* eap = reinterpret_cast<const float4*>(ea[cur]);
        #pragma unroll
        for (int k = 0; k < 32; ++k) {
            float4 v = eap[k];   // 16B broadcast read (same addr across lanes)
            h2 a0 = __builtin_bit_cast(h2, v.x);
            h2 a1 = __builtin_bit_cast(h2, v.y);
            h2 a2 = __builtin_bit_cast(h2, v.z);
            h2 a3 = __builtin_bit_cast(h2, v.w);
            acc0 = dot2(mreg[4 * k + 0], a0, acc0);
            acc1 = dot2(mreg[4 * k + 1], a1, acc1);
            acc2 = dot2(mreg[4 * k + 2], a2, acc2);
            acc3 = dot2(mreg[4 * k + 3], a3, acc3);
        }
        float s = (acc0 + acc1) + (acc2 + acc3);

        anew = et + m_base + __logf(s);

        // wave max of new alpha
        wm = anew;
        #pragma unroll
        for (int off = 32; off; off >>= 1) wm = fmaxf(wm, __shfl_xor(wm, off));
        if (lane == 0) wmaxbuf[t & 1][wv] = wm;

        // stale (one-step-old) exact max from previous step's buffer
        const float* pb = wmaxbuf[(t - 1) & 1];
        m_base = fmaxf(fmaxf(pb[0], pb[1]), fmaxf(pb[2], pb[3])) + 4.f;

        float eav = fminf(__expf(anew - m_base), 60000.f);
        reinterpret_cast<_Float16*>(ea[cur ^ 1])[tid] = (_Float16)eav;
        cur ^= 1;
        __syncthreads();   // single barrier per step
    }

    // epilogue: logZ_b = LSE_i(alpha_last)
    wm = anew;
    #pragma unroll
    for (int off = 32; off; off >>= 1) wm = fmaxf(wm, __shfl_xor(wm, off));
    if (lane == 0) wmaxbuf[0][wv] = wm;
    __syncthreads();
    float m = fmaxf(fmaxf(wmaxbuf[0][0], wmaxbuf[0][1]),
                    fmaxf(wmaxbuf[0][2], wmaxbuf[0][3]));
    float e = __expf(anew - m);
    #pragma unroll
    for (int off = 32; off; off >>= 1) e += __shfl_xor(e, off);
    if (lane == 0) wsum[wv] = e;
    __syncthreads();
    if (tid == 0) {
        bout[b] = m + __logf(((wsum[0] + wsum[1]) + (wsum[2] + wsum[3])));
    }
}

__global__ void crf_reduce(const float* __restrict__ bout, float* __restrict__ out)
{
    const int tid = threadIdx.x;  // 128 threads
    float v = bout[tid];
    #pragma unroll
    for (int off = 32; off; off >>= 1) v += __shfl_xor(v, off);
    __shared__ float sred[2];
    if ((tid & 63) == 0) sred[tid >> 6] = v;
    __syncthreads();
    if (tid == 0) out[0] = sred[0] + sred[1];
}

extern "C" void kernel_launch(void* const* d_in, const int* in_sizes, int n_in,
                              void* d_out, int out_size, void* d_ws, size_t ws_size,
                              hipStream_t stream)
{
    const float* emis  = (const float*)d_in[0];
    const float* trans = (const float*)d_in[1];
    const int*   words = (const int*)d_in[2];
    float* out  = (float*)d_out;
    float* bout = (float*)d_ws;   // 128 floats of scratch

    crf_forward<<<NB, 256, 0, stream>>>(emis, trans, words, bout);
    crf_reduce<<<1, 128, 0, stream>>>(bout, out);
}